// Round 1
// baseline (1521.777 us; speedup 1.0000x reference)
//
#include <hip/hip_runtime.h>
#include <math.h>

#define NN 50000
#define NF 512
#define NH 512
#define NK 16

// ---------------- GEMM: xw[M,512] = feat[M,512] @ W[512,512], fp32 ----------------
#define BM 64
#define BN 64
#define BK 32

__global__ __launch_bounds__(256) void gemm_xw(const float* __restrict__ A,
                                               const float* __restrict__ B,
                                               float* __restrict__ C, int M) {
  __shared__ float As[BK][BM + 4];   // transposed A tile: As[k][row]
  __shared__ float Bs[BK][BN + 4];
  const int tid = threadIdx.x;
  const int tx = tid & 15;
  const int ty = tid >> 4;
  const int block_row = blockIdx.y * BM;
  const int block_col = blockIdx.x * BN;

  float acc[4][4] = {};

  for (int k0 = 0; k0 < NF; k0 += BK) {
    // A tile: 64 rows x 32 cols = 512 float4 slots, 2 per thread
#pragma unroll
    for (int l = 0; l < 2; ++l) {
      int slot = tid + l * 256;
      int r = slot >> 3;            // 0..63
      int c4 = (slot & 7) * 4;      // 0..28
      int gr = block_row + r;
      float4 v = make_float4(0.f, 0.f, 0.f, 0.f);
      if (gr < M) v = *(const float4*)(A + (size_t)gr * NF + k0 + c4);
      As[c4 + 0][r] = v.x; As[c4 + 1][r] = v.y;
      As[c4 + 2][r] = v.z; As[c4 + 3][r] = v.w;
    }
    // B tile: 32 rows x 64 cols
#pragma unroll
    for (int l = 0; l < 2; ++l) {
      int slot = tid + l * 256;
      int r = slot >> 4;            // 0..31
      int c4 = (slot & 15) * 4;     // 0..60
      float4 v = *(const float4*)(B + (size_t)(k0 + r) * NH + block_col + c4);
      *(float4*)(&Bs[r][c4]) = v;
    }
    __syncthreads();
#pragma unroll
    for (int k = 0; k < BK; ++k) {
      float4 ra = *(const float4*)(&As[k][ty * 4]);
      float4 rb = *(const float4*)(&Bs[k][tx * 4]);
      float a[4] = {ra.x, ra.y, ra.z, ra.w};
      float b[4] = {rb.x, rb.y, rb.z, rb.w};
#pragma unroll
      for (int i = 0; i < 4; ++i)
#pragma unroll
        for (int j = 0; j < 4; ++j)
          acc[i][j] = fmaf(a[i], b[j], acc[i][j]);
    }
    __syncthreads();
  }
#pragma unroll
  for (int i = 0; i < 4; ++i) {
    int gr = block_row + ty * 4 + i;
    if (gr < M) {
      float4 v = make_float4(acc[i][0], acc[i][1], acc[i][2], acc[i][3]);
      *(float4*)(C + (size_t)gr * NH + block_col + tx * 4) = v;
    }
  }
}

// ---------------- edge histogram + degrees ----------------
__global__ void hist_kernel(const int* __restrict__ src, const int* __restrict__ dst,
                            const float* __restrict__ gv, int* __restrict__ counts,
                            float* __restrict__ deg, int E) {
  int e = blockIdx.x * blockDim.x + threadIdx.x;
  if (e < E) {
    atomicAdd(&counts[src[e]], 1);
    atomicAdd(&deg[dst[e]], gv[e]);
  }
}

// ---------------- exclusive scan of counts -> offs, cursor (single block, 1024 thr) ----------------
__global__ __launch_bounds__(1024) void scan_kernel(const int* __restrict__ counts,
                                                    int* __restrict__ offs,
                                                    int* __restrict__ cursor, int n) {
  __shared__ int wsum[16];
  __shared__ int carry_sh;
  const int lane = threadIdx.x & 63;
  const int wave = threadIdx.x >> 6;
  if (threadIdx.x == 0) carry_sh = 0;
  __syncthreads();
  for (int base = 0; base < n; base += 1024) {
    int i = base + threadIdx.x;
    int v = (i < n) ? counts[i] : 0;
    // inclusive wave scan
    int x = v;
#pragma unroll
    for (int d = 1; d < 64; d <<= 1) {
      int y = __shfl_up(x, d, 64);
      if (lane >= d) x += y;
    }
    if (lane == 63) wsum[wave] = x;
    __syncthreads();
    if (wave == 0 && lane < 16) {
      int w = wsum[lane];
      int xx = w;
#pragma unroll
      for (int d = 1; d < 16; d <<= 1) {
        int y = __shfl_up(xx, d, 16);
        if (lane >= d) xx += y;
      }
      wsum[lane] = xx - w;   // exclusive wave offset
    }
    __syncthreads();
    int exc = carry_sh + wsum[wave] + x - v;
    if (i < n) { offs[i] = exc; cursor[i] = exc; }
    __syncthreads();
    if (threadIdx.x == 1023) carry_sh = carry_sh + wsum[15] + x;
    __syncthreads();
  }
  if (threadIdx.x == 0) offs[n] = carry_sh;
}

// ---------------- scatter edges into CSR ----------------
__global__ void scatter_kernel(const int* __restrict__ src, const int* __restrict__ dst,
                               const float* __restrict__ gn, int* __restrict__ cursor,
                               int* __restrict__ edst, float* __restrict__ eg, int E) {
  int e = blockIdx.x * blockDim.x + threadIdx.x;
  if (e < E) {
    int pos = atomicAdd(&cursor[src[e]], 1);
    edst[pos] = dst[e];
    eg[pos] = gn[e];
  }
}

// ---------------- fused per-node: SpMM row + bias + selu + proj(512x16) + softmax ----------------
__global__ __launch_bounds__(256) void node_kernel(const float* __restrict__ xw,
                                                   const int* __restrict__ offs,
                                                   const int* __restrict__ edst,
                                                   const float* __restrict__ eg,
                                                   const float* __restrict__ bias,
                                                   const float* __restrict__ Wt,
                                                   const float* __restrict__ bt,
                                                   float* __restrict__ assign, int n) {
  int node = blockIdx.x;
  if (node >= n) return;
  const int t = threadIdx.x;
  const int beg = offs[node], end = offs[node + 1];
  float a0 = 0.f, a1 = 0.f;
  for (int e = beg; e < end; ++e) {
    int d = edst[e];
    float g = eg[e];
    float2 v = *(const float2*)(xw + (size_t)d * NH + t * 2);
    a0 = fmaf(g, v.x, a0);
    a1 = fmaf(g, v.y, a1);
  }
  a0 += bias[t * 2];
  a1 += bias[t * 2 + 1];
  const float SC = 1.0507009873554805f, AL = 1.6732632423543772f;
  a0 = (a0 > 0.f) ? SC * a0 : SC * AL * (expf(a0) - 1.f);
  a1 = (a1 > 0.f) ? SC * a1 : SC * AL * (expf(a1) - 1.f);
  // partial logits
  float p[NK];
  const float* w0 = Wt + (size_t)(t * 2) * NK;
#pragma unroll
  for (int k = 0; k < NK; ++k) p[k] = a0 * w0[k] + a1 * w0[NK + k];
  // reduce across 64-lane wave
#pragma unroll
  for (int off = 32; off >= 1; off >>= 1)
#pragma unroll
    for (int k = 0; k < NK; ++k) p[k] += __shfl_down(p[k], off, 64);
  __shared__ float red[4][NK];
  int wave = t >> 6, lane = t & 63;
  if (lane == 0) {
#pragma unroll
    for (int k = 0; k < NK; ++k) red[wave][k] = p[k];
  }
  __syncthreads();
  if (t < NK) {
    float l = red[0][t] + red[1][t] + red[2][t] + red[3][t] + bt[t];
    float m = l;
#pragma unroll
    for (int off = 8; off >= 1; off >>= 1) m = fmaxf(m, __shfl_xor(m, off, 16));
    float ex = expf(l - m);
    float s = ex;
#pragma unroll
    for (int off = 8; off >= 1; off >>= 1) s += __shfl_xor(s, off, 16);
    assign[(size_t)node * NK + t] = ex / s;
  }
}

// ---------------- cs[k] = sum_i S[i][k];  nl[k] = sum_i S[i][k]*deg[i] ----------------
__global__ void reduce_cs_nl(const float* __restrict__ assign, const float* __restrict__ deg,
                             float* __restrict__ acc, int n) {
  float cs[NK] = {}, nl[NK] = {};
  for (int i = blockIdx.x * blockDim.x + threadIdx.x; i < n; i += gridDim.x * blockDim.x) {
    float d = deg[i];
    const float4* ap = (const float4*)(assign + (size_t)i * NK);
#pragma unroll
    for (int q = 0; q < 4; ++q) {
      float4 a = ap[q];
      cs[q * 4 + 0] += a.x; cs[q * 4 + 1] += a.y;
      cs[q * 4 + 2] += a.z; cs[q * 4 + 3] += a.w;
      nl[q * 4 + 0] = fmaf(a.x, d, nl[q * 4 + 0]);
      nl[q * 4 + 1] = fmaf(a.y, d, nl[q * 4 + 1]);
      nl[q * 4 + 2] = fmaf(a.z, d, nl[q * 4 + 2]);
      nl[q * 4 + 3] = fmaf(a.w, d, nl[q * 4 + 3]);
    }
  }
#pragma unroll
  for (int off = 32; off >= 1; off >>= 1) {
#pragma unroll
    for (int k = 0; k < NK; ++k) {
      cs[k] += __shfl_down(cs[k], off, 64);
      nl[k] += __shfl_down(nl[k], off, 64);
    }
  }
  if ((threadIdx.x & 63) == 0) {
#pragma unroll
    for (int k = 0; k < NK; ++k) {
      atomicAdd(&acc[k], cs[k]);
      atomicAdd(&acc[NK + k], nl[k]);
    }
  }
}

// ---------------- tp = sum_e g[e] * <S[src[e]], S[dst[e]]> ----------------
__global__ void trace_kernel(const int* __restrict__ src, const int* __restrict__ dst,
                             const float* __restrict__ gv, const float* __restrict__ assign,
                             float* __restrict__ acc, int E) {
  float t = 0.f;
  for (int e = blockIdx.x * blockDim.x + threadIdx.x; e < E; e += gridDim.x * blockDim.x) {
    int s = src[e], d = dst[e];
    const float4* as = (const float4*)(assign + (size_t)s * NK);
    const float4* ad = (const float4*)(assign + (size_t)d * NK);
    float dot = 0.f;
#pragma unroll
    for (int q = 0; q < 4; ++q) {
      float4 x = as[q], y = ad[q];
      dot += x.x * y.x + x.y * y.y + x.z * y.z + x.w * y.w;
    }
    t = fmaf(gv[e], dot, t);
  }
#pragma unroll
  for (int off = 32; off >= 1; off >>= 1) t += __shfl_down(t, off, 64);
  if ((threadIdx.x & 63) == 0) atomicAdd(&acc[2 * NK], t);
}

// ---------------- final scalar ----------------
__global__ void final_kernel(const float* __restrict__ acc, float* __restrict__ out,
                             int E, int n) {
  if (threadIdx.x == 0 && blockIdx.x == 0) {
    float sn = 0.f, sc = 0.f;
#pragma unroll
    for (int k = 0; k < NK; ++k) {
      sc += acc[k] * acc[k];
      sn += acc[NK + k] * acc[NK + k];
    }
    float tp = acc[2 * NK];
    float twoE = 2.0f * (float)E;
    float spectral = -(tp - sn / twoE) / twoE;
    float closs = (sqrtf(sc) / (float)n) * 4.0f - 1.0f;   // sqrt(K)=4, CLUSTER_REG=1
    out[0] = spectral + closs;
  }
}

extern "C" void kernel_launch(void* const* d_in, const int* in_sizes, int n_in,
                              void* d_out, int out_size, void* d_ws, size_t ws_size,
                              hipStream_t stream) {
  const int*   src  = (const int*)d_in[0];
  const int*   dst  = (const int*)d_in[1];
  const float* gv   = (const float*)d_in[2];
  const float* gn   = (const float*)d_in[3];
  const float* feat = (const float*)d_in[4];
  const float* W    = (const float*)d_in[5];
  const float* b    = (const float*)d_in[6];
  const float* Wt   = (const float*)d_in[7];
  const float* bt   = (const float*)d_in[8];
  const int E = in_sizes[0];
  const int N = in_sizes[4] / NF;

  char* ws = (char*)d_ws;
  size_t off = 0;
  auto alloc = [&](size_t bytes) {
    void* p = ws + off;
    off += (bytes + 255) & ~(size_t)255;
    return p;
  };
  float* xw     = (float*)alloc((size_t)N * NH * sizeof(float));   // 102.4 MB
  int*   counts = (int*)alloc((size_t)N * sizeof(int));
  int*   offs   = (int*)alloc((size_t)(N + 1) * sizeof(int));
  int*   cursor = (int*)alloc((size_t)N * sizeof(int));
  float* deg    = (float*)alloc((size_t)N * sizeof(float));
  int*   edst   = (int*)alloc((size_t)E * sizeof(int));
  float* eg     = (float*)alloc((size_t)E * sizeof(float));
  float* assign = (float*)alloc((size_t)N * NK * sizeof(float));
  float* acc    = (float*)alloc(64 * sizeof(float));
  (void)ws_size; (void)n_in; (void)out_size;

  hipMemsetAsync(counts, 0, (size_t)N * sizeof(int), stream);
  hipMemsetAsync(deg, 0, (size_t)N * sizeof(float), stream);
  hipMemsetAsync(acc, 0, 64 * sizeof(float), stream);

  dim3 ggrid(NH / BN, (N + BM - 1) / BM);
  gemm_xw<<<ggrid, 256, 0, stream>>>(feat, W, xw, N);

  int eblocks = (E + 255) / 256;
  hist_kernel<<<eblocks, 256, 0, stream>>>(src, dst, gv, counts, deg, E);
  scan_kernel<<<1, 1024, 0, stream>>>(counts, offs, cursor, N);
  scatter_kernel<<<eblocks, 256, 0, stream>>>(src, dst, gn, cursor, edst, eg, E);

  node_kernel<<<N, 256, 0, stream>>>(xw, offs, edst, eg, b, Wt, bt, assign, N);

  reduce_cs_nl<<<128, 256, 0, stream>>>(assign, deg, acc, N);
  trace_kernel<<<4096, 256, 0, stream>>>(src, dst, gv, assign, acc, E);
  final_kernel<<<1, 64, 0, stream>>>(acc, (float*)d_out, E, N);
}

// Round 2
// 1212.446 us; speedup vs baseline: 1.2551x; 1.2551x over previous
//
#include <hip/hip_runtime.h>
#include <math.h>

#define NN 50000
#define NF 512
#define NH 512
#define NK 16

typedef __attribute__((ext_vector_type(8))) short bf16x8;
typedef __attribute__((ext_vector_type(4))) float f32x4;

__device__ __forceinline__ unsigned short f2bf(float f) {
  unsigned u = __float_as_uint(f);
  unsigned r = (u + 0x7fffu + ((u >> 16) & 1u)) >> 16;
  return (unsigned short)r;
}

// ---------------- fp32 -> bf16 feature conversion ----------------
__global__ __launch_bounds__(256) void conv_feat(const float* __restrict__ X,
                                                 unsigned short* __restrict__ Xb, int n4) {
  // n4 = total elems / 4
  for (int i = blockIdx.x * blockDim.x + threadIdx.x; i < n4; i += gridDim.x * blockDim.x) {
    float4 v = *(const float4*)(X + (size_t)i * 4);
    ushort4 o;
    o.x = f2bf(v.x); o.y = f2bf(v.y); o.z = f2bf(v.z); o.w = f2bf(v.w);
    *(ushort4*)(Xb + (size_t)i * 4) = o;
  }
}

// ---------------- W -> packed bf16: Bp[(k>>3)*512 + col)*8 + (k&7)] ----------------
__global__ __launch_bounds__(256) void conv_w(const float* __restrict__ W,
                                              unsigned short* __restrict__ Bp) {
  int idx = blockIdx.x * blockDim.x + threadIdx.x;   // 512*512 threads
  int k = idx >> 9, col = idx & 511;
  Bp[((size_t)(k >> 3) * 512 + col) * 8 + (k & 7)] = f2bf(W[idx]);
}

// ---------------- GEMM: xw_bf[Mpad,512] = feat_bf @ W (bf16 MFMA) ----------------
#define GBM 128
#define GBN 128
#define GBK 32

__global__ __launch_bounds__(256) void gemm_bf16(const unsigned short* __restrict__ A,
                                                 const unsigned short* __restrict__ Bp,
                                                 unsigned short* __restrict__ C, int M) {
  __shared__ bf16x8 Abuf[512];   // [kc 0..3][row 0..127] -> chunk of 8 k-elems
  __shared__ bf16x8 Bbuf[512];   // [kc 0..3][col 0..127]
  const int tid = threadIdx.x;
  const int lane = tid & 63;
  const int w = tid >> 6;            // 0..3
  const int wr = w >> 1, wc = w & 1; // 2x2 waves of 64x64
  const int bm0 = blockIdx.y * GBM;
  const int bn0 = blockIdx.x * GBN;

  f32x4 acc[4][4];
#pragma unroll
  for (int m = 0; m < 4; ++m)
#pragma unroll
    for (int n = 0; n < 4; ++n)
      acc[m][n] = (f32x4){0.f, 0.f, 0.f, 0.f};

  for (int k0 = 0; k0 < NF; k0 += GBK) {
    // stage: 512 chunks of 16B each for A and B, 2 per thread each
#pragma unroll
    for (int c = 0; c < 2; ++c) {
      int slot = c * 256 + tid;
      int kc = slot >> 7;          // 0..3
      int rc = slot & 127;         // row (A) / col (B)
      int gr = bm0 + rc; if (gr > M - 1) gr = M - 1;
      bf16x8 va = *(const bf16x8*)(A + (size_t)gr * NF + k0 + kc * 8);
      Abuf[slot] = va;
      int kcg = (k0 >> 3) + kc;
      bf16x8 vb = *(const bf16x8*)(Bp + ((size_t)kcg * NH + bn0 + rc) * 8);
      Bbuf[slot] = vb;
    }
    __syncthreads();
    bf16x8 af[4], bfr[4];
#pragma unroll
    for (int m = 0; m < 4; ++m)
      af[m] = Abuf[(lane >> 4) * 128 + wr * 64 + m * 16 + (lane & 15)];
#pragma unroll
    for (int n = 0; n < 4; ++n)
      bfr[n] = Bbuf[(lane >> 4) * 128 + wc * 64 + n * 16 + (lane & 15)];
#pragma unroll
    for (int m = 0; m < 4; ++m)
#pragma unroll
      for (int n = 0; n < 4; ++n)
        acc[m][n] = __builtin_amdgcn_mfma_f32_16x16x32_bf16(af[m], bfr[n], acc[m][n], 0, 0, 0);
    __syncthreads();
  }
  // C/D layout: col = lane&15, row = (lane>>4)*4 + r   [verified m89/m91]
#pragma unroll
  for (int m = 0; m < 4; ++m) {
    int grow_base = bm0 + wr * 64 + m * 16 + (lane >> 4) * 4;
#pragma unroll
    for (int r = 0; r < 4; ++r) {
      int grow = grow_base + r;
#pragma unroll
      for (int n = 0; n < 4; ++n) {
        int gcol = bn0 + wc * 64 + n * 16 + (lane & 15);
        C[(size_t)grow * NH + gcol] = f2bf(acc[m][n][r]);
      }
    }
  }
}

// ---------------- edge histogram + degrees ----------------
__global__ void hist_kernel(const int* __restrict__ src, const int* __restrict__ dst,
                            const float* __restrict__ gv, int* __restrict__ counts,
                            float* __restrict__ deg, int E) {
  int e = blockIdx.x * blockDim.x + threadIdx.x;
  if (e < E) {
    atomicAdd(&counts[src[e]], 1);
    atomicAdd(&deg[dst[e]], gv[e]);
  }
}

// ---------------- exclusive scan (single block, 1024 thr) ----------------
__global__ __launch_bounds__(1024) void scan_kernel(const int* __restrict__ counts,
                                                    int* __restrict__ offs,
                                                    int* __restrict__ cursor, int n) {
  __shared__ int wsum[16];
  __shared__ int carry_sh;
  const int lane = threadIdx.x & 63;
  const int wave = threadIdx.x >> 6;
  if (threadIdx.x == 0) carry_sh = 0;
  __syncthreads();
  for (int base = 0; base < n; base += 1024) {
    int i = base + threadIdx.x;
    int v = (i < n) ? counts[i] : 0;
    int x = v;
#pragma unroll
    for (int d = 1; d < 64; d <<= 1) {
      int y = __shfl_up(x, d, 64);
      if (lane >= d) x += y;
    }
    if (lane == 63) wsum[wave] = x;
    __syncthreads();
    if (wave == 0 && lane < 16) {
      int w = wsum[lane];
      int xx = w;
#pragma unroll
      for (int d = 1; d < 16; d <<= 1) {
        int y = __shfl_up(xx, d, 16);
        if (lane >= d) xx += y;
      }
      wsum[lane] = xx - w;
    }
    __syncthreads();
    int exc = carry_sh + wsum[wave] + x - v;
    if (i < n) { offs[i] = exc; cursor[i] = exc; }
    __syncthreads();
    if (threadIdx.x == 1023) carry_sh = carry_sh + wsum[15] + x;
    __syncthreads();
  }
  if (threadIdx.x == 0) offs[n] = carry_sh;
}

// ---------------- scatter edges into CSR ----------------
__global__ void scatter_kernel(const int* __restrict__ src, const int* __restrict__ dst,
                               const float* __restrict__ gn, int* __restrict__ cursor,
                               int* __restrict__ edst, float* __restrict__ eg, int E) {
  int e = blockIdx.x * blockDim.x + threadIdx.x;
  if (e < E) {
    int pos = atomicAdd(&cursor[src[e]], 1);
    edst[pos] = dst[e];
    eg[pos] = gn[e];
  }
}

// ---------------- fused per-node: SpMM (bf16 xw) + bias + selu + proj + softmax ----------------
__global__ __launch_bounds__(256) void node_kernel(const unsigned short* __restrict__ xw,
                                                   const int* __restrict__ offs,
                                                   const int* __restrict__ edst,
                                                   const float* __restrict__ eg,
                                                   const float* __restrict__ bias,
                                                   const float* __restrict__ Wt,
                                                   const float* __restrict__ bt,
                                                   float* __restrict__ assign, int n) {
  int node = blockIdx.x;
  if (node >= n) return;
  const int t = threadIdx.x;
  const int beg = offs[node], end = offs[node + 1];
  float a0 = 0.f, a1 = 0.f;
  for (int e = beg; e < end; ++e) {
    int d = edst[e];
    float g = eg[e];
    unsigned v = ((const unsigned*)(xw + (size_t)d * NH))[t];
    float lo = __uint_as_float(v << 16);
    float hi = __uint_as_float(v & 0xFFFF0000u);
    a0 = fmaf(g, lo, a0);
    a1 = fmaf(g, hi, a1);
  }
  a0 += bias[t * 2];
  a1 += bias[t * 2 + 1];
  const float SC = 1.0507009873554805f, AL = 1.6732632423543772f;
  a0 = (a0 > 0.f) ? SC * a0 : SC * AL * (expf(a0) - 1.f);
  a1 = (a1 > 0.f) ? SC * a1 : SC * AL * (expf(a1) - 1.f);
  float p[NK];
  const float* w0 = Wt + (size_t)(t * 2) * NK;
#pragma unroll
  for (int k = 0; k < NK; ++k) p[k] = a0 * w0[k] + a1 * w0[NK + k];
#pragma unroll
  for (int off = 32; off >= 1; off >>= 1)
#pragma unroll
    for (int k = 0; k < NK; ++k) p[k] += __shfl_down(p[k], off, 64);
  __shared__ float red[4][NK];
  int wave = t >> 6, lane = t & 63;
  if (lane == 0) {
#pragma unroll
    for (int k = 0; k < NK; ++k) red[wave][k] = p[k];
  }
  __syncthreads();
  if (t < NK) {
    float l = red[0][t] + red[1][t] + red[2][t] + red[3][t] + bt[t];
    float m = l;
#pragma unroll
    for (int off = 8; off >= 1; off >>= 1) m = fmaxf(m, __shfl_xor(m, off, 16));
    float ex = expf(l - m);
    float s = ex;
#pragma unroll
    for (int off = 8; off >= 1; off >>= 1) s += __shfl_xor(s, off, 16);
    assign[(size_t)node * NK + t] = ex / s;
  }
}

// ---------------- cs[k], nl[k] reductions ----------------
__global__ void reduce_cs_nl(const float* __restrict__ assign, const float* __restrict__ deg,
                             float* __restrict__ acc, int n) {
  float cs[NK] = {}, nl[NK] = {};
  for (int i = blockIdx.x * blockDim.x + threadIdx.x; i < n; i += gridDim.x * blockDim.x) {
    float d = deg[i];
    const float4* ap = (const float4*)(assign + (size_t)i * NK);
#pragma unroll
    for (int q = 0; q < 4; ++q) {
      float4 a = ap[q];
      cs[q * 4 + 0] += a.x; cs[q * 4 + 1] += a.y;
      cs[q * 4 + 2] += a.z; cs[q * 4 + 3] += a.w;
      nl[q * 4 + 0] = fmaf(a.x, d, nl[q * 4 + 0]);
      nl[q * 4 + 1] = fmaf(a.y, d, nl[q * 4 + 1]);
      nl[q * 4 + 2] = fmaf(a.z, d, nl[q * 4 + 2]);
      nl[q * 4 + 3] = fmaf(a.w, d, nl[q * 4 + 3]);
    }
  }
#pragma unroll
  for (int off = 32; off >= 1; off >>= 1) {
#pragma unroll
    for (int k = 0; k < NK; ++k) {
      cs[k] += __shfl_down(cs[k], off, 64);
      nl[k] += __shfl_down(nl[k], off, 64);
    }
  }
  if ((threadIdx.x & 63) == 0) {
#pragma unroll
    for (int k = 0; k < NK; ++k) {
      atomicAdd(&acc[k], cs[k]);
      atomicAdd(&acc[NK + k], nl[k]);
    }
  }
}

// ---------------- tp = sum_e g[e] * <S[src],S[dst]> ----------------
__global__ void trace_kernel(const int* __restrict__ src, const int* __restrict__ dst,
                             const float* __restrict__ gv, const float* __restrict__ assign,
                             float* __restrict__ acc, int E) {
  float t = 0.f;
  for (int e = blockIdx.x * blockDim.x + threadIdx.x; e < E; e += gridDim.x * blockDim.x) {
    int s = src[e], d = dst[e];
    const float4* as = (const float4*)(assign + (size_t)s * NK);
    const float4* ad = (const float4*)(assign + (size_t)d * NK);
    float dot = 0.f;
#pragma unroll
    for (int q = 0; q < 4; ++q) {
      float4 x = as[q], y = ad[q];
      dot += x.x * y.x + x.y * y.y + x.z * y.z + x.w * y.w;
    }
    t = fmaf(gv[e], dot, t);
  }
#pragma unroll
  for (int off = 32; off >= 1; off >>= 1) t += __shfl_down(t, off, 64);
  if ((threadIdx.x & 63) == 0) atomicAdd(&acc[2 * NK], t);
}

// ---------------- final scalar ----------------
__global__ void final_kernel(const float* __restrict__ acc, float* __restrict__ out,
                             int E, int n) {
  if (threadIdx.x == 0 && blockIdx.x == 0) {
    float sn = 0.f, sc = 0.f;
#pragma unroll
    for (int k = 0; k < NK; ++k) {
      sc += acc[k] * acc[k];
      sn += acc[NK + k] * acc[NK + k];
    }
    float tp = acc[2 * NK];
    float twoE = 2.0f * (float)E;
    float spectral = -(tp - sn / twoE) / twoE;
    float closs = (sqrtf(sc) / (float)n) * 4.0f - 1.0f;
    out[0] = spectral + closs;
  }
}

extern "C" void kernel_launch(void* const* d_in, const int* in_sizes, int n_in,
                              void* d_out, int out_size, void* d_ws, size_t ws_size,
                              hipStream_t stream) {
  const int*   src  = (const int*)d_in[0];
  const int*   dst  = (const int*)d_in[1];
  const float* gv   = (const float*)d_in[2];
  const float* gn   = (const float*)d_in[3];
  const float* feat = (const float*)d_in[4];
  const float* W    = (const float*)d_in[5];
  const float* b    = (const float*)d_in[6];
  const float* Wt   = (const float*)d_in[7];
  const float* bt   = (const float*)d_in[8];
  const int E = in_sizes[0];
  const int N = in_sizes[4] / NF;
  const int Mblocks = (N + GBM - 1) / GBM;
  const int Mpad = Mblocks * GBM;

  char* ws = (char*)d_ws;
  size_t off = 0;
  auto alloc = [&](size_t bytes) {
    void* p = ws + off;
    off += (bytes + 255) & ~(size_t)255;
    return p;
  };
  unsigned short* feat_bf = (unsigned short*)alloc((size_t)N * NF * sizeof(unsigned short));
  unsigned short* Wp      = (unsigned short*)alloc((size_t)NF * NH * sizeof(unsigned short));
  unsigned short* xw      = (unsigned short*)alloc((size_t)Mpad * NH * sizeof(unsigned short));
  int*   counts = (int*)alloc((size_t)N * sizeof(int));
  int*   offs   = (int*)alloc((size_t)(N + 1) * sizeof(int));
  int*   cursor = (int*)alloc((size_t)N * sizeof(int));
  float* deg    = (float*)alloc((size_t)N * sizeof(float));
  int*   edst   = (int*)alloc((size_t)E * sizeof(int));
  float* eg     = (float*)alloc((size_t)E * sizeof(float));
  float* assign = (float*)alloc((size_t)N * NK * sizeof(float));
  float* acc    = (float*)alloc(64 * sizeof(float));
  (void)ws_size; (void)n_in; (void)out_size;

  hipMemsetAsync(counts, 0, (size_t)N * sizeof(int), stream);
  hipMemsetAsync(deg, 0, (size_t)N * sizeof(float), stream);
  hipMemsetAsync(acc, 0, 64 * sizeof(float), stream);

  conv_feat<<<2048, 256, 0, stream>>>(feat, feat_bf, N * NF / 4);
  conv_w<<<(NF * NH) / 256, 256, 0, stream>>>(W, Wp);

  dim3 ggrid(NH / GBN, Mblocks);
  gemm_bf16<<<ggrid, 256, 0, stream>>>(feat_bf, Wp, xw, N);

  int eblocks = (E + 255) / 256;
  hist_kernel<<<eblocks, 256, 0, stream>>>(src, dst, gv, counts, deg, E);
  scan_kernel<<<1, 1024, 0, stream>>>(counts, offs, cursor, N);
  scatter_kernel<<<eblocks, 256, 0, stream>>>(src, dst, gn, cursor, edst, eg, E);

  node_kernel<<<N, 256, 0, stream>>>(xw, offs, edst, eg, b, Wt, bt, assign, N);

  reduce_cs_nl<<<128, 256, 0, stream>>>(assign, deg, acc, N);
  trace_kernel<<<4096, 256, 0, stream>>>(src, dst, gv, assign, acc, E);
  final_kernel<<<1, 64, 0, stream>>>(acc, (float*)d_out, E, N);
}

// Round 3
// 1095.448 us; speedup vs baseline: 1.3892x; 1.1068x over previous
//
#include <hip/hip_runtime.h>
#include <math.h>

#define NN 50000
#define NF 512
#define NH 512
#define NK 16

typedef __attribute__((ext_vector_type(8))) short bf16x8;
typedef __attribute__((ext_vector_type(4))) float f32x4;

__device__ __forceinline__ unsigned short f2bf(float f) {
  unsigned u = __float_as_uint(f);
  unsigned r = (u + 0x7fffu + ((u >> 16) & 1u)) >> 16;
  return (unsigned short)r;
}

// ---------------- W -> packed bf16: Bp[((k>>3)*512 + col)*8 + (k&7)] ----------------
__global__ __launch_bounds__(256) void conv_w(const float* __restrict__ W,
                                              unsigned short* __restrict__ Bp) {
  int idx = blockIdx.x * blockDim.x + threadIdx.x;   // 512*512 threads
  int k = idx >> 9, col = idx & 511;
  Bp[((size_t)(k >> 3) * 512 + col) * 8 + (k & 7)] = f2bf(W[idx]);
}

// ---------------- GEMM: xw_bf[Mpad,512] = bf16(feat) @ W (bf16 MFMA, fused cvt) ----------------
#define GBM 128
#define GBN 128
#define GBK 32

__global__ __launch_bounds__(256) void gemm_bf16(const float* __restrict__ A,
                                                 const unsigned short* __restrict__ Bp,
                                                 unsigned short* __restrict__ C, int M) {
  __shared__ bf16x8 Abuf[512];   // [kc 0..3][row 0..127]
  __shared__ bf16x8 Bbuf[512];   // [kc 0..3][col 0..127]
  const int tid = threadIdx.x;
  const int lane = tid & 63;
  const int w = tid >> 6;
  const int wr = w >> 1, wc = w & 1;
  const int bm0 = blockIdx.y * GBM;
  const int bn0 = blockIdx.x * GBN;

  f32x4 acc[4][4];
#pragma unroll
  for (int m = 0; m < 4; ++m)
#pragma unroll
    for (int n = 0; n < 4; ++n)
      acc[m][n] = (f32x4){0.f, 0.f, 0.f, 0.f};

  for (int k0 = 0; k0 < NF; k0 += GBK) {
#pragma unroll
    for (int c = 0; c < 2; ++c) {
      int slot = c * 256 + tid;
      int kc = slot >> 7;
      int rc = slot & 127;
      int gr = bm0 + rc; if (gr > M - 1) gr = M - 1;
      const float* ap = A + (size_t)gr * NF + k0 + kc * 8;
      float4 f0 = *(const float4*)ap;
      float4 f1 = *(const float4*)(ap + 4);
      bf16x8 va;
      va[0] = (short)f2bf(f0.x); va[1] = (short)f2bf(f0.y);
      va[2] = (short)f2bf(f0.z); va[3] = (short)f2bf(f0.w);
      va[4] = (short)f2bf(f1.x); va[5] = (short)f2bf(f1.y);
      va[6] = (short)f2bf(f1.z); va[7] = (short)f2bf(f1.w);
      Abuf[slot] = va;
      int kcg = (k0 >> 3) + kc;
      Bbuf[slot] = *(const bf16x8*)(Bp + ((size_t)kcg * NH + bn0 + rc) * 8);
    }
    __syncthreads();
    bf16x8 af[4], bfr[4];
#pragma unroll
    for (int m = 0; m < 4; ++m)
      af[m] = Abuf[(lane >> 4) * 128 + wr * 64 + m * 16 + (lane & 15)];
#pragma unroll
    for (int n = 0; n < 4; ++n)
      bfr[n] = Bbuf[(lane >> 4) * 128 + wc * 64 + n * 16 + (lane & 15)];
#pragma unroll
    for (int m = 0; m < 4; ++m)
#pragma unroll
      for (int n = 0; n < 4; ++n)
        acc[m][n] = __builtin_amdgcn_mfma_f32_16x16x32_bf16(af[m], bfr[n], acc[m][n], 0, 0, 0);
    __syncthreads();
  }
#pragma unroll
  for (int m = 0; m < 4; ++m) {
    int grow_base = bm0 + wr * 64 + m * 16 + (lane >> 4) * 4;
#pragma unroll
    for (int r = 0; r < 4; ++r) {
      int grow = grow_base + r;
#pragma unroll
      for (int n = 0; n < 4; ++n) {
        int gcol = bn0 + wc * 64 + n * 16 + (lane & 15);
        C[(size_t)grow * NH + gcol] = f2bf(acc[m][n][r]);
      }
    }
  }
}

// ---------------- edge histogram + degrees ----------------
__global__ void hist_kernel(const int* __restrict__ src, const int* __restrict__ dst,
                            const float* __restrict__ gv, int* __restrict__ counts,
                            float* __restrict__ deg, int E) {
  int e = blockIdx.x * blockDim.x + threadIdx.x;
  if (e < E) {
    atomicAdd(&counts[src[e]], 1);
    atomicAdd(&deg[dst[e]], gv[e]);
  }
}

// ---------------- exclusive scan, 4 elems/thread (single block, 1024 thr) ----------------
__global__ __launch_bounds__(1024) void scan_kernel(const int* __restrict__ counts,
                                                    int* __restrict__ offs,
                                                    int* __restrict__ cursor, int n) {
  __shared__ int wsum[16];
  __shared__ int carry_sh;
  const int lane = threadIdx.x & 63;
  const int wave = threadIdx.x >> 6;
  if (threadIdx.x == 0) carry_sh = 0;
  __syncthreads();
  for (int base = 0; base < n; base += 4096) {
    int i0 = base + threadIdx.x * 4;
    int c0 = 0, c1 = 0, c2 = 0, c3 = 0;
    if (i0 + 3 < n) {
      int4 v = *(const int4*)(counts + i0);
      c0 = v.x; c1 = v.y; c2 = v.z; c3 = v.w;
    } else {
      if (i0 < n)     c0 = counts[i0];
      if (i0 + 1 < n) c1 = counts[i0 + 1];
      if (i0 + 2 < n) c2 = counts[i0 + 2];
      if (i0 + 3 < n) c3 = counts[i0 + 3];
    }
    int s = c0 + c1 + c2 + c3;
    int x = s;
#pragma unroll
    for (int d = 1; d < 64; d <<= 1) {
      int y = __shfl_up(x, d, 64);
      if (lane >= d) x += y;
    }
    if (lane == 63) wsum[wave] = x;
    __syncthreads();
    if (wave == 0 && lane < 16) {
      int w = wsum[lane];
      int xx = w;
#pragma unroll
      for (int d = 1; d < 16; d <<= 1) {
        int y = __shfl_up(xx, d, 16);
        if (lane >= d) xx += y;
      }
      wsum[lane] = xx - w;
    }
    __syncthreads();
    int exc = carry_sh + wsum[wave] + x - s;
    if (i0 < n)     { offs[i0]     = exc;           cursor[i0]     = exc; }
    if (i0 + 1 < n) { offs[i0 + 1] = exc + c0;      cursor[i0 + 1] = exc + c0; }
    if (i0 + 2 < n) { offs[i0 + 2] = exc + c0 + c1; cursor[i0 + 2] = exc + c0 + c1; }
    if (i0 + 3 < n) { offs[i0 + 3] = exc + c0 + c1 + c2; cursor[i0 + 3] = exc + c0 + c1 + c2; }
    __syncthreads();
    if (threadIdx.x == 1023) carry_sh = carry_sh + wsum[15] + x;
    __syncthreads();
  }
  if (threadIdx.x == 0) offs[n] = carry_sh;
}

// ---------------- scatter edges into CSR ----------------
__global__ void scatter_kernel(const int* __restrict__ src, const int* __restrict__ dst,
                               const float* __restrict__ gn, int* __restrict__ cursor,
                               int* __restrict__ edst, float* __restrict__ eg, int E) {
  int e = blockIdx.x * blockDim.x + threadIdx.x;
  if (e < E) {
    int pos = atomicAdd(&cursor[src[e]], 1);
    edst[pos] = dst[e];
    eg[pos] = gn[e];
  }
}

// ---------------- fused per-node: dst-sort + SpMM + bias + selu + proj + softmax ----------------
__global__ __launch_bounds__(256) void node_kernel(const unsigned short* __restrict__ xw,
                                                   const int* __restrict__ offs,
                                                   const int* __restrict__ edst,
                                                   const float* __restrict__ eg,
                                                   const float* __restrict__ bias,
                                                   const float* __restrict__ Wt,
                                                   const float* __restrict__ bt,
                                                   float* __restrict__ assign, int n) {
  __shared__ int sk[256];
  __shared__ float sv[256];
  __shared__ int ok[256];
  __shared__ float ov[256];
  __shared__ float red[4][NK];
  int node = blockIdx.x;
  if (node >= n) return;
  const int t = threadIdx.x;
  const int beg = offs[node], end = offs[node + 1];
  float a0 = 0.f, a1 = 0.f;

  for (int cbeg = beg; cbeg < end; cbeg += 256) {
    int d = end - cbeg; if (d > 256) d = 256;
    if (t < d) { sk[t] = edst[cbeg + t]; sv[t] = eg[cbeg + t]; }
    __syncthreads();
    if (t < d) {
      int k = sk[t];
      int rank = 0;
      for (int j = 0; j < d; ++j) {
        int kj = sk[j];
        rank += (kj < k) || (kj == k && j < t);
      }
      ok[rank] = k; ov[rank] = sv[t];
    }
    __syncthreads();
    // sorted gather: concurrently-running blocks sweep dst-space together -> L2 locality
    for (int e = 0; e < d; ++e) {
      int dn = ok[e];
      float g = ov[e];
      unsigned v = ((const unsigned*)(xw + (size_t)dn * NH))[t];
      float lo = __uint_as_float(v << 16);
      float hi = __uint_as_float(v & 0xFFFF0000u);
      a0 = fmaf(g, lo, a0);
      a1 = fmaf(g, hi, a1);
    }
    __syncthreads();
  }

  a0 += bias[t * 2];
  a1 += bias[t * 2 + 1];
  const float SC = 1.0507009873554805f, AL = 1.6732632423543772f;
  a0 = (a0 > 0.f) ? SC * a0 : SC * AL * (expf(a0) - 1.f);
  a1 = (a1 > 0.f) ? SC * a1 : SC * AL * (expf(a1) - 1.f);
  float p[NK];
  const float* w0 = Wt + (size_t)(t * 2) * NK;
#pragma unroll
  for (int k = 0; k < NK; ++k) p[k] = a0 * w0[k] + a1 * w0[NK + k];
#pragma unroll
  for (int off = 32; off >= 1; off >>= 1)
#pragma unroll
    for (int k = 0; k < NK; ++k) p[k] += __shfl_down(p[k], off, 64);
  int wave = t >> 6, lane = t & 63;
  if (lane == 0) {
#pragma unroll
    for (int k = 0; k < NK; ++k) red[wave][k] = p[k];
  }
  __syncthreads();
  if (t < NK) {
    float l = red[0][t] + red[1][t] + red[2][t] + red[3][t] + bt[t];
    float m = l;
#pragma unroll
    for (int off = 8; off >= 1; off >>= 1) m = fmaxf(m, __shfl_xor(m, off, 16));
    float ex = expf(l - m);
    float s = ex;
#pragma unroll
    for (int off = 8; off >= 1; off >>= 1) s += __shfl_xor(s, off, 16);
    assign[(size_t)node * NK + t] = ex / s;
  }
}

// ---------------- cs[k], nl[k] reductions ----------------
__global__ void reduce_cs_nl(const float* __restrict__ assign, const float* __restrict__ deg,
                             float* __restrict__ acc, int n) {
  float cs[NK] = {}, nl[NK] = {};
  for (int i = blockIdx.x * blockDim.x + threadIdx.x; i < n; i += gridDim.x * blockDim.x) {
    float d = deg[i];
    const float4* ap = (const float4*)(assign + (size_t)i * NK);
#pragma unroll
    for (int q = 0; q < 4; ++q) {
      float4 a = ap[q];
      cs[q * 4 + 0] += a.x; cs[q * 4 + 1] += a.y;
      cs[q * 4 + 2] += a.z; cs[q * 4 + 3] += a.w;
      nl[q * 4 + 0] = fmaf(a.x, d, nl[q * 4 + 0]);
      nl[q * 4 + 1] = fmaf(a.y, d, nl[q * 4 + 1]);
      nl[q * 4 + 2] = fmaf(a.z, d, nl[q * 4 + 2]);
      nl[q * 4 + 3] = fmaf(a.w, d, nl[q * 4 + 3]);
    }
  }
#pragma unroll
  for (int off = 32; off >= 1; off >>= 1) {
#pragma unroll
    for (int k = 0; k < NK; ++k) {
      cs[k] += __shfl_down(cs[k], off, 64);
      nl[k] += __shfl_down(nl[k], off, 64);
    }
  }
  if ((threadIdx.x & 63) == 0) {
#pragma unroll
    for (int k = 0; k < NK; ++k) {
      atomicAdd(&acc[k], cs[k]);
      atomicAdd(&acc[NK + k], nl[k]);
    }
  }
}

// ---------------- tp = sum_e g[e] * <S[src],S[dst]> ----------------
__global__ void trace_kernel(const int* __restrict__ src, const int* __restrict__ dst,
                             const float* __restrict__ gv, const float* __restrict__ assign,
                             float* __restrict__ acc, int E) {
  float t = 0.f;
  for (int e = blockIdx.x * blockDim.x + threadIdx.x; e < E; e += gridDim.x * blockDim.x) {
    int s = src[e], d = dst[e];
    const float4* as = (const float4*)(assign + (size_t)s * NK);
    const float4* ad = (const float4*)(assign + (size_t)d * NK);
    float dot = 0.f;
#pragma unroll
    for (int q = 0; q < 4; ++q) {
      float4 x = as[q], y = ad[q];
      dot += x.x * y.x + x.y * y.y + x.z * y.z + x.w * y.w;
    }
    t = fmaf(gv[e], dot, t);
  }
#pragma unroll
  for (int off = 32; off >= 1; off >>= 1) t += __shfl_down(t, off, 64);
  if ((threadIdx.x & 63) == 0) atomicAdd(&acc[2 * NK], t);
}

// ---------------- final scalar ----------------
__global__ void final_kernel(const float* __restrict__ acc, float* __restrict__ out,
                             int E, int n) {
  if (threadIdx.x == 0 && blockIdx.x == 0) {
    float sn = 0.f, sc = 0.f;
#pragma unroll
    for (int k = 0; k < NK; ++k) {
      sc += acc[k] * acc[k];
      sn += acc[NK + k] * acc[NK + k];
    }
    float tp = acc[2 * NK];
    float twoE = 2.0f * (float)E;
    float spectral = -(tp - sn / twoE) / twoE;
    float closs = (sqrtf(sc) / (float)n) * 4.0f - 1.0f;
    out[0] = spectral + closs;
  }
}

extern "C" void kernel_launch(void* const* d_in, const int* in_sizes, int n_in,
                              void* d_out, int out_size, void* d_ws, size_t ws_size,
                              hipStream_t stream) {
  const int*   src  = (const int*)d_in[0];
  const int*   dst  = (const int*)d_in[1];
  const float* gv   = (const float*)d_in[2];
  const float* gn   = (const float*)d_in[3];
  const float* feat = (const float*)d_in[4];
  const float* W    = (const float*)d_in[5];
  const float* b    = (const float*)d_in[6];
  const float* Wt   = (const float*)d_in[7];
  const float* bt   = (const float*)d_in[8];
  const int E = in_sizes[0];
  const int N = in_sizes[4] / NF;
  const int Mblocks = (N + GBM - 1) / GBM;
  const int Mpad = Mblocks * GBM;

  char* ws = (char*)d_ws;
  size_t off = 0;
  auto alloc = [&](size_t bytes) {
    void* p = ws + off;
    off += (bytes + 255) & ~(size_t)255;
    return p;
  };
  unsigned short* Wp      = (unsigned short*)alloc((size_t)NF * NH * sizeof(unsigned short));
  unsigned short* xw      = (unsigned short*)alloc((size_t)Mpad * NH * sizeof(unsigned short));
  int*   counts = (int*)alloc((size_t)N * sizeof(int));
  int*   offs   = (int*)alloc((size_t)(N + 1) * sizeof(int));
  int*   cursor = (int*)alloc((size_t)N * sizeof(int));
  float* deg    = (float*)alloc((size_t)N * sizeof(float));
  int*   edst   = (int*)alloc((size_t)E * sizeof(int));
  float* eg     = (float*)alloc((size_t)E * sizeof(float));
  float* assign = (float*)alloc((size_t)N * NK * sizeof(float));
  float* acc    = (float*)alloc(64 * sizeof(float));
  (void)ws_size; (void)n_in; (void)out_size;

  hipMemsetAsync(counts, 0, (size_t)N * sizeof(int), stream);
  hipMemsetAsync(deg, 0, (size_t)N * sizeof(float), stream);
  hipMemsetAsync(acc, 0, 64 * sizeof(float), stream);

  conv_w<<<(NF * NH) / 256, 256, 0, stream>>>(W, Wp);

  dim3 ggrid(NH / GBN, Mblocks);
  gemm_bf16<<<ggrid, 256, 0, stream>>>(feat, Wp, xw, N);

  int eblocks = (E + 255) / 256;
  hist_kernel<<<eblocks, 256, 0, stream>>>(src, dst, gv, counts, deg, E);
  scan_kernel<<<1, 1024, 0, stream>>>(counts, offs, cursor, N);
  scatter_kernel<<<eblocks, 256, 0, stream>>>(src, dst, gn, cursor, edst, eg, E);

  node_kernel<<<N, 256, 0, stream>>>(xw, offs, edst, eg, b, Wt, bt, assign, N);

  reduce_cs_nl<<<128, 256, 0, stream>>>(assign, deg, acc, N);
  trace_kernel<<<4096, 256, 0, stream>>>(src, dst, gv, assign, acc, E);
  final_kernel<<<1, 64, 0, stream>>>(acc, (float*)d_out, E, N);
}